// Round 2
// baseline (34358.820 us; speedup 1.0000x reference)
//
#include <hip/hip_runtime.h>
#include <stdint.h>

#define BB 64
#define TT 64
#define OBSD 128
#define DD 512
#define NS 3
#define ACT 16
#define DONE 5
#define LN_EPS 1e-3f

typedef unsigned short u16;
typedef __attribute__((ext_vector_type(8))) short short8;
typedef __attribute__((ext_vector_type(4))) float f32x4;

__device__ __forceinline__ float b2f(u16 u) {
    return __uint_as_float(((unsigned int)u) << 16);
}
__device__ __forceinline__ u16 f2b(float f) {
    unsigned int x = __float_as_uint(f);
    unsigned int r = x + 0x7fffu + ((x >> 16) & 1u);
    return (u16)(r >> 16);
}
__device__ __forceinline__ float sigm(float x) { return 1.f / (1.f + expf(-x)); }
__device__ __forceinline__ float ldin(const void* p, long i, int isf) {
    return isf ? ((const float*)p)[i] : b2f(((const u16*)p)[i]);
}
__device__ __forceinline__ void stout(void* p, long i, float v, int isf) {
    if (isf) ((float*)p)[i] = v; else ((u16*)p)[i] = f2b(v);
}

// ---------------- dtype detector ----------------
// bf16 data ~N(0,0.02^2): every u16 has exponent in [0x70,0x88].
// f32 data: even-index u16 = low mantissa half -> ~10% plausible.
// bf16-rounded-but-f32-stored: even u16 all zero -> classified f32 (correct).
__global__ void detect_k(const void* probe, int* flag) {
    if (threadIdx.x == 0 && blockIdx.x == 0) {
        const u16* u = (const u16*)probe;
        int nz = 0, npl = 0;
        for (int j = 0; j < 128; ++j) {
            u16 v = u[2 * j];
            if (v == 0) { nz++; continue; }
            int e = (v >> 7) & 0xff;
            if (e >= 0x70 && e <= 0x88) npl++;
        }
        int nonzero = 128 - nz;
        *flag = (npl * 2 > nonzero) ? 0 : 1;  // 0 = bf16, 1 = f32
    }
}

// ---------------- stage small params -> f32 ws ----------------
struct StageArgs { const void* src[16]; float* dst[16]; int n[16]; const int* flag; };
__global__ __launch_bounds__(256) void stage_k(StageArgs s) {
    int isf = *s.flag;
    int z = blockIdx.y;
    int i = blockIdx.x * 256 + threadIdx.x;
    if (s.src[z] && i < s.n[z]) s.dst[z][i] = ldin(s.src[z], i, isf);
}

// ---------------- elementwise convert -> bf16 ----------------
__global__ __launch_bounds__(256) void convb_k(const void* src, u16* dst, int n, const int* flag) {
    int isf = *flag;
    int i = blockIdx.x * 256 + threadIdx.x;
    if (i < n) dst[i] = isf ? f2b(((const float*)src)[i]) : ((const u16*)src)[i];
}

// ---------------- transpose [K,N] -> bf16 [N,K] ----------------
__global__ __launch_bounds__(256) void transpose_k(const void* in, u16* out, int K, int N,
                                                   const int* flag) {
    __shared__ u16 tile[32][33];
    int isf = *flag;
    long zoff = (long)blockIdx.z * K * N;
    int kb = blockIdx.y * 32, nb = blockIdx.x * 32;
    int tx = threadIdx.x & 31, ty = threadIdx.x >> 5;
    for (int r = ty; r < 32; r += 8) {
        long idx = zoff + (long)(kb + r) * N + nb + tx;
        tile[r][tx] = isf ? f2b(((const float*)in)[idx]) : ((const u16*)in)[idx];
    }
    __syncthreads();
    for (int r = ty; r < 32; r += 8)
        out[zoff + (long)(nb + r) * K + kb + tx] = tile[tx][r];
}

// ---------------- init: task_emb gather + m state ----------------
__global__ __launch_bounds__(256) void init_k(const void* emb, const int* env, const void* prevm,
                                              float* task_f, u16* task_b, u16* m_b, float* m_f,
                                              const int* flag) {
    int isf = *flag;
    int b = blockIdx.x, tid = threadIdx.x;
    int e = env[b];
    for (int j = tid; j < DD; j += 256) {
        float v = ldin(emb, (long)e * DD + j, isf);
        task_f[b * DD + j] = v;
        task_b[b * DD + j] = f2b(v);
    }
    for (int j = tid; j < NS * DD; j += 256) {
        float v = ldin(prevm, (long)b * NS * DD + j, isf);
        m_b[b * NS * DD + j] = f2b(v);
        m_f[b * NS * DD + j] = v;
    }
}

// ---------------- generic MFMA GEMM: Y = act(X @ W + bias) ----------------
struct Seg { const u16* p; int rs; int zs; };
struct GemmArgs {
    Seg seg[4];
    int nseg, segw_sh;
    const u16* Wt;       // [N,K] bf16
    const float* bias;   // staged f32
    float* yf; u16* yb;
    int y_rs, y_zs;
    int K, act;          // act: 0 none, 1 relu, 2 leaky(0.3)
};

__global__ __launch_bounds__(256) void gemm_mfma(GemmArgs g) {
    const int lane = threadIdx.x & 63;
    const int wave = threadIdx.x >> 6;
    const int l16 = lane & 15;
    const int quad = lane >> 4;
    const int z = blockIdx.z;
    const int n0 = blockIdx.x * 64 + wave * 16;
    const int m_base = blockIdx.y * 64;
    const int n = n0 + l16;

    f32x4 acc0 = {0.f, 0.f, 0.f, 0.f};
    f32x4 acc1 = acc0, acc2 = acc0, acc3 = acc0;

    const int segw = 1 << g.segw_sh;
    const u16* wp = g.Wt + (long)n * g.K + quad * 8;

    for (int s = 0; s < g.nseg; ++s) {
        const int rs = g.seg[s].rs;
        const u16* base = g.seg[s].p + (long)z * g.seg[s].zs + quad * 8;
        const u16* a0 = base + (long)(m_base + l16) * rs;
        const u16* a1 = a0 + (long)16 * rs;
        const u16* a2 = a0 + (long)32 * rs;
        const u16* a3 = a0 + (long)48 * rs;
        for (int k = 0; k < segw; k += 32) {
            short8 av0 = *(const short8*)(a0 + k);
            short8 av1 = *(const short8*)(a1 + k);
            short8 av2 = *(const short8*)(a2 + k);
            short8 av3 = *(const short8*)(a3 + k);
            short8 bv = *(const short8*)wp;
            wp += 32;
            acc0 = __builtin_amdgcn_mfma_f32_16x16x32_bf16(av0, bv, acc0, 0, 0, 0);
            acc1 = __builtin_amdgcn_mfma_f32_16x16x32_bf16(av1, bv, acc1, 0, 0, 0);
            acc2 = __builtin_amdgcn_mfma_f32_16x16x32_bf16(av2, bv, acc2, 0, 0, 0);
            acc3 = __builtin_amdgcn_mfma_f32_16x16x32_bf16(av3, bv, acc3, 0, 0, 0);
        }
    }

    float bb = g.bias[n];
    f32x4 accs[4] = {acc0, acc1, acc2, acc3};
#pragma unroll
    for (int mt = 0; mt < 4; ++mt) {
#pragma unroll
        for (int r = 0; r < 4; ++r) {
            int m = m_base + mt * 16 + quad * 4 + r;
            float v = accs[mt][r] + bb;
            if (g.act == 1) v = v > 0.f ? v : 0.f;
            else if (g.act == 2) v = v > 0.f ? v : 0.3f * v;
            long off = (long)z * g.y_zs + (long)m * g.y_rs + n;
            if (g.yf) g.yf[off] = v;
            if (g.yb) g.yb[off] = f2b(v);
        }
    }
}

// ---------------- block reduction helper ----------------
__device__ __forceinline__ float block_sum(float v, float* red) {
    red[threadIdx.x] = v;
    __syncthreads();
    for (int s = 128; s > 0; s >>= 1) {
        if (threadIdx.x < s) red[threadIdx.x] += red[threadIdx.x + s];
        __syncthreads();
    }
    float r = red[0];
    __syncthreads();
    return r;
}

// ---------------- gate kernel (com: W1=1536, 2 srcs; dec: W1=1024, 1 src) ----------------
struct GateArgs {
    const float* a; int W1;
    const float* gw; const float* gb;   // staged f32
    const float* s0; int s0_rs;
    const float* s1; int s1_rs;
    float* out_f; u16* out_b; int out_rs;
};

__global__ __launch_bounds__(256) void gate_k(GateArgs g) {
    __shared__ float red[256];
    __shared__ float u[DD];
    int b = blockIdx.x, tid = threadIdx.x;
    const int arow_w = g.W1 + DD;
    const float* arow = g.a + (long)b * arow_w;

    float s = 0.f, ss = 0.f;
    for (int j = tid; j < g.W1; j += 256) { float v = arow[j]; s += v; ss += v * v; }
    float tot = block_sum(s, red);
    float tot2 = block_sum(ss, red);
    float mu = tot / (float)g.W1;
    float var = tot2 / (float)g.W1 - mu * mu;
    float inv = rsqrtf(var + LN_EPS);

    float s2 = 0.f, ss2 = 0.f;
    for (int d = tid; d < DD; d += 256) {
        float g0 = sigm((arow[d] - mu) * inv * g.gw[d] + g.gb[d]);
        float val = g0 * g.s0[(long)b * g.s0_rs + d];
        if (g.s1) {
            float g1 = sigm((arow[DD + d] - mu) * inv * g.gw[DD + d] + g.gb[DD + d]);
            val += g1 * g.s1[(long)b * g.s1_rs + d];
        }
        int co = g.W1 - DD + d;
        float gc = sigm((arow[co] - mu) * inv * g.gw[co] + g.gb[co]);
        val += gc * arow[g.W1 + d];
        u[d] = val;
        s2 += val; ss2 += val * val;
    }
    float t2 = block_sum(s2, red);
    float t22 = block_sum(ss2, red);
    float mu2 = t2 / (float)DD;
    float var2 = t22 / (float)DD - mu2 * mu2;
    float inv2 = rsqrtf(var2 + LN_EPS);
    for (int d = tid; d < DD; d += 256) {
        float v = (u[d] - mu2) * inv2;
        long o = (long)b * g.out_rs + d;
        g.out_f[o] = v;
        g.out_b[o] = f2b(v);
    }
}

// ---------------- beta / p_hat / m-update kernel ----------------
struct PbmArgs {
    const float* h1; const float* Wd2; const float* bd2;
    const float* cand_f;
    float* m_f; u16* m_b;
    float* chl_f;     // slot 0 = new m[:,0]
    float* pp;        // [B,4]: p0,p1,p2,p_end
    void* out; long ph_base;  // element idx = ph_base + b*TT*4 + k
    const int* flag;
};

__global__ __launch_bounds__(256) void pbm_k(PbmArgs g) {
    __shared__ float red[256];
    __shared__ float sc[3];
    int b = blockIdx.x, tid = threadIdx.x;
    int isf = *g.flag;
    float dot[3];
    for (int n = 0; n < 3; ++n) {
        const float* hr = g.h1 + ((long)b * 3 + n) * DD;
        float sacc = 0.f;
        for (int k = tid; k < DD; k += 256) sacc += hr[k] * g.Wd2[k];
        dot[n] = block_sum(sacc, red);
    }
    if (tid == 0) {
        float bd = g.bd2[0];
        float b0 = sigm(dot[0] + bd), b1 = sigm(dot[1] + bd), b2 = sigm(dot[2] + bd);
        float ph0 = (1.f - b2) * (1.f - b1) * (1.f - b0);
        float ph1 = b0 * (1.f - b2) * (1.f - b1);
        float ph2 = b1 * (1.f - b2);
        float ph3 = b2;
        float sum = fmaxf(ph1 + ph2 + ph3, 1e-30f);
        float p0 = ph1 / sum, p1 = ph2 / sum, p2 = ph3 / sum;
        sc[0] = p0 + p1 + p2; sc[1] = p1 + p2; sc[2] = p2;
        g.pp[b * 4 + 0] = p0; g.pp[b * 4 + 1] = p1;
        g.pp[b * 4 + 2] = p2; g.pp[b * 4 + 3] = ph0;
        long ob = g.ph_base + (long)b * (TT * (NS + 1));
        stout(g.out, ob + 0, ph0, isf);
        stout(g.out, ob + 1, ph1, isf);
        stout(g.out, ob + 2, ph2, isf);
        stout(g.out, ob + 3, ph3, isf);
    }
    __syncthreads();
    for (int idx = tid; idx < NS * DD; idx += 256) {
        int n = idx >> 9, d = idx & (DD - 1);
        float r = sc[n];
        long o = (long)b * NS * DD + idx;
        float v = g.m_f[o] * (1.f - r) + g.cand_f[o] * r;
        g.m_f[o] = v;
        g.m_b[o] = f2b(v);
        if (n == 0) g.chl_f[(long)b * NS * DD + d] = v;
    }
}

// ---------------- final: einsum + Wa head + log-probs ----------------
struct FinArgs {
    const float* chl; const float* pp;
    const float* task; const float* inp;  // inp row stride T*DD
    const float* Wa; const float* ba;
    void* out; long o_base;  // element idx = o_base + b*TT*ACT + pos
    const int* flag;
};

__global__ __launch_bounds__(256) void final_k(FinArgs g) {
    __shared__ float o3[3 * DD];
    __shared__ float sl[ACT - 1];
    int b = blockIdx.x, tid = threadIdx.x;
    const float* pb = g.pp + b * 4;
    const float* c = g.chl + (long)b * NS * DD;
    for (int d = tid; d < DD; d += 256) {
        o3[d] = pb[0] * c[d] + pb[1] * c[DD + d] + pb[2] * c[2 * DD + d];
        o3[DD + d] = g.task[b * DD + d];
        o3[2 * DD + d] = g.inp[(long)b * (TT * DD) + d];
    }
    __syncthreads();
    if (tid < 240) {
        int a = tid >> 4, kk = tid & 15;
        float sacc = 0.f;
        for (int k = kk; k < 3 * DD; k += 16) sacc += o3[k] * g.Wa[k * (ACT - 1) + a];
        sacc += __shfl_down(sacc, 8);
        sacc += __shfl_down(sacc, 4);
        sacc += __shfl_down(sacc, 2);
        sacc += __shfl_down(sacc, 1);
        if (kk == 0) sl[a] = sacc + g.ba[a];
    }
    __syncthreads();
    if (tid == 0) {
        int isf = *g.flag;
        float mx = -1e30f;
        for (int a = 0; a < ACT - 1; ++a) mx = fmaxf(mx, sl[a]);
        float se = 0.f;
        for (int a = 0; a < ACT - 1; ++a) se += expf(sl[a] - mx);
        float lse = logf(se);
        float pe = pb[3];
        pe = fminf(fmaxf(pe, 1e-6f), 1.f - 1e-6f);
        float l1me = logf(1.f - pe);
        long ob = g.o_base + (long)b * (TT * ACT);
        for (int a = 0; a < ACT - 1; ++a) {
            float lg = sl[a] - mx - lse + l1me;
            int pos = (a < DONE) ? a : a + 1;
            stout(g.out, ob + pos, lg, isf);
        }
        stout(g.out, ob + DONE, logf(pe), isf);
    }
}

// ---------------- host ----------------
static inline Seg mkseg(const u16* p, int rs, int zs) { Seg s; s.p = p; s.rs = rs; s.zs = zs; return s; }

extern "C" void kernel_launch(void* const* d_in, const int* in_sizes, int n_in,
                              void* d_out, int out_size, void* d_ws, size_t ws_size,
                              hipStream_t stream) {
    const void* obs = d_in[0];
    const int* env = (const int*)d_in[1];
    const void* prevm = d_in[2];
    const void* emb = d_in[4];
    const void* Wobs = d_in[5];
    const void* bobs = d_in[6];
    const void* comW1 = d_in[7];
    const void* comb1 = d_in[8];
    const void* comW2 = d_in[9];
    const void* comb2 = d_in[10];
    const void* comg = d_in[11];
    const void* combeta = d_in[12];
    const void* decW1 = d_in[13];
    const void* decb1 = d_in[14];
    const void* decW2 = d_in[15];
    const void* decb2 = d_in[16];
    const void* decg = d_in[17];
    const void* decbeta = d_in[18];
    const void* Wd1 = d_in[19];
    const void* bd1 = d_in[20];
    const void* Wd2 = d_in[21];
    const void* bd2 = d_in[22];
    const void* Wa = d_in[23];
    const void* ba = d_in[24];

    char* p = (char*)d_ws;
    auto carve = [&](size_t bytes) -> char* {
        char* r = p;
        p += (bytes + 255) & ~(size_t)255;
        return r;
    };
    int* flag = (int*)carve(256);
    u16* comW1t = (u16*)carve(3ull * 2048 * 2048 * 2);
    u16* comW2t = (u16*)carve(3ull * 2048 * 2048 * 2);
    u16* decW1t = (u16*)carve(2ull * 2048 * 1536 * 2);
    u16* decW2t = (u16*)carve(2ull * 1536 * 2048 * 2);
    u16* Wd1t = (u16*)carve(512ull * 2048 * 2);
    u16* Wobst = (u16*)carve(512ull * 128 * 2);
    u16* obs_b = (u16*)carve((size_t)BB * TT * OBSD * 2);
    float* obs_inp_f = (float*)carve((size_t)BB * TT * DD * 4);
    u16* obs_inp_b = (u16*)carve((size_t)BB * TT * DD * 2);
    float* task_f = (float*)carve((size_t)BB * DD * 4);
    u16* task_b = (u16*)carve((size_t)BB * DD * 2);
    float* m_f = (float*)carve((size_t)BB * NS * DD * 4);
    u16* m_b = (u16*)carve((size_t)BB * NS * DD * 2);
    float* cand_f = (float*)carve((size_t)BB * NS * DD * 4);
    u16* cand_b = (u16*)carve((size_t)BB * NS * DD * 2);
    float* chl_f = (float*)carve((size_t)BB * NS * DD * 4);
    u16* chl_b = (u16*)carve((size_t)BB * NS * DD * 2);
    float* a_f = (float*)carve((size_t)BB * 2048 * 4);
    u16* a1_b = (u16*)carve((size_t)BB * 2048 * 2);
    float* h1_f = (float*)carve((size_t)BB * NS * DD * 4);
    float* pp = (float*)carve((size_t)BB * 4 * 4);
    // staged f32 params
    float* st_bobs = (float*)carve(512 * 4);
    float* st_comb1 = (float*)carve(3 * 2048 * 4);
    float* st_comb2 = (float*)carve(3 * 2048 * 4);
    float* st_comg = (float*)carve(3 * 1536 * 4);
    float* st_combeta = (float*)carve(3 * 1536 * 4);
    float* st_decb1 = (float*)carve(2 * 2048 * 4);
    float* st_decb2 = (float*)carve(2 * 1536 * 4);
    float* st_decg = (float*)carve(2 * 1024 * 4);
    float* st_decbeta = (float*)carve(2 * 1024 * 4);
    float* st_bd1 = (float*)carve(512 * 4);
    float* st_Wd2 = (float*)carve(512 * 4);
    float* st_bd2 = (float*)carve(4);
    float* st_Wa = (float*)carve(1536 * 15 * 4);
    float* st_ba = (float*)carve(15 * 4);

    dim3 blk(256);

    detect_k<<<dim3(1), dim3(64), 0, stream>>>(Wobs, flag);

    {
        StageArgs sa{};
        const void* srcs[14] = {bobs, comb1, comb2, comg, combeta, decb1, decb2,
                                decg, decbeta, bd1, Wd2, bd2, Wa, ba};
        float* dsts[14] = {st_bobs, st_comb1, st_comb2, st_comg, st_combeta, st_decb1,
                           st_decb2, st_decg, st_decbeta, st_bd1, st_Wd2, st_bd2, st_Wa, st_ba};
        int ns[14] = {512, 6144, 6144, 4608, 4608, 4096, 3072, 2048, 2048, 512, 512, 1, 23040, 15};
        for (int i = 0; i < 14; ++i) { sa.src[i] = srcs[i]; sa.dst[i] = dsts[i]; sa.n[i] = ns[i]; }
        sa.flag = flag;
        stage_k<<<dim3(90, 14, 1), blk, 0, stream>>>(sa);
    }

    transpose_k<<<dim3(16, 4, 1), blk, 0, stream>>>(Wobs, Wobst, 128, 512, flag);
    transpose_k<<<dim3(64, 64, 3), blk, 0, stream>>>(comW1, comW1t, 2048, 2048, flag);
    transpose_k<<<dim3(64, 64, 3), blk, 0, stream>>>(comW2, comW2t, 2048, 2048, flag);
    transpose_k<<<dim3(64, 48, 2), blk, 0, stream>>>(decW1, decW1t, 1536, 2048, flag);
    transpose_k<<<dim3(48, 64, 2), blk, 0, stream>>>(decW2, decW2t, 2048, 1536, flag);
    transpose_k<<<dim3(16, 64, 1), blk, 0, stream>>>(Wd1, Wd1t, 2048, 512, flag);
    convb_k<<<dim3((BB * TT * OBSD + 255) / 256), blk, 0, stream>>>(obs, obs_b, BB * TT * OBSD, flag);
    init_k<<<dim3(BB), blk, 0, stream>>>(emb, env, prevm, task_f, task_b, m_b, m_f, flag);

    {   // obs_inp = obs @ W_obs + b_obs   (4096 x 512, K=128)
        GemmArgs ga{};
        ga.seg[0] = mkseg(obs_b, OBSD, 0);
        ga.nseg = 1; ga.segw_sh = 7;
        ga.Wt = Wobst; ga.bias = st_bobs;
        ga.yf = obs_inp_f; ga.yb = obs_inp_b; ga.y_rs = DD; ga.y_zs = 0;
        ga.K = OBSD; ga.act = 0;
        gemm_mfma<<<dim3(DD / 64, (BB * TT) / 64, 1), blk, 0, stream>>>(ga);
    }

    for (int t = 0; t < TT; ++t) {
        const u16* inpb_t = obs_inp_b + t * DD;    // row stride T*DD
        const float* inpf_t = obs_inp_f + t * DD;  // row stride T*DD

        for (int ii = NS - 1; ii >= 0; --ii) {
            GemmArgs g1{};
            g1.seg[0] = (ii == NS - 1) ? mkseg(inpb_t, TT * DD, 0)
                                       : mkseg(cand_b + (ii + 1) * DD, NS * DD, 0);
            g1.seg[1] = mkseg(m_b + ii * DD, NS * DD, 0);
            g1.seg[2] = mkseg(inpb_t, TT * DD, 0);
            g1.seg[3] = mkseg(task_b, DD, 0);
            g1.nseg = 4; g1.segw_sh = 9;
            g1.Wt = comW1t + (size_t)ii * 2048 * 2048;
            g1.bias = st_comb1 + ii * 2048;
            g1.yf = nullptr; g1.yb = a1_b; g1.y_rs = 2048; g1.y_zs = 0;
            g1.K = 2048; g1.act = 1;
            gemm_mfma<<<dim3(32, 1, 1), blk, 0, stream>>>(g1);

            GemmArgs g2{};
            for (int s4 = 0; s4 < 4; ++s4) g2.seg[s4] = mkseg(a1_b + s4 * 512, 2048, 0);
            g2.nseg = 4; g2.segw_sh = 9;
            g2.Wt = comW2t + (size_t)ii * 2048 * 2048;
            g2.bias = st_comb2 + ii * 2048;
            g2.yf = a_f; g2.yb = nullptr; g2.y_rs = 2048; g2.y_zs = 0;
            g2.K = 2048; g2.act = 0;
            gemm_mfma<<<dim3(32, 1, 1), blk, 0, stream>>>(g2);

            GateArgs gg{};
            gg.a = a_f; gg.W1 = 1536;
            gg.gw = st_comg + ii * 1536; gg.gb = st_combeta + ii * 1536;
            if (ii == NS - 1) { gg.s0 = inpf_t; gg.s0_rs = TT * DD; }
            else { gg.s0 = cand_f + (ii + 1) * DD; gg.s0_rs = NS * DD; }
            gg.s1 = m_f + ii * DD; gg.s1_rs = NS * DD;
            gg.out_f = cand_f + ii * DD; gg.out_b = cand_b + ii * DD; gg.out_rs = NS * DD;
            gate_k<<<dim3(BB), blk, 0, stream>>>(gg);
        }

        {   // dist head: h1[b,n,:] = leaky_relu(dist_in @ Wd1 + bd1)
            GemmArgs gd{};
            gd.seg[0] = mkseg(inpb_t, TT * DD, 0);
            gd.seg[1] = mkseg(task_b, DD, 0);
            gd.seg[2] = mkseg(m_b, NS * DD, DD);
            gd.seg[3] = mkseg(cand_b, NS * DD, DD);
            gd.nseg = 4; gd.segw_sh = 9;
            gd.Wt = Wd1t; gd.bias = st_bd1;
            gd.yf = h1_f; gd.yb = nullptr; gd.y_rs = NS * DD; gd.y_zs = DD;
            gd.K = 2048; gd.act = 2;
            gemm_mfma<<<dim3(DD / 64, 1, NS), blk, 0, stream>>>(gd);
        }

        {
            PbmArgs pb{};
            pb.h1 = h1_f; pb.Wd2 = st_Wd2; pb.bd2 = st_bd2; pb.cand_f = cand_f;
            pb.m_f = m_f; pb.m_b = m_b; pb.chl_f = chl_f; pb.pp = pp;
            pb.out = d_out; pb.ph_base = (long)BB * TT * ACT + (long)t * (NS + 1);
            pb.flag = flag;
            pbm_k<<<dim3(BB), blk, 0, stream>>>(pb);
        }

        for (int j = 0; j < 2; ++j) {
            GemmArgs d1{};
            d1.seg[0] = (j == 0) ? mkseg(m_b, NS * DD, 0) : mkseg(chl_b + DD, NS * DD, 0);
            d1.seg[1] = mkseg(inpb_t, TT * DD, 0);
            d1.seg[2] = mkseg(task_b, DD, 0);
            d1.nseg = 3; d1.segw_sh = 9;
            d1.Wt = decW1t + (size_t)j * 2048 * 1536;
            d1.bias = st_decb1 + j * 2048;
            d1.yf = nullptr; d1.yb = a1_b; d1.y_rs = 2048; d1.y_zs = 0;
            d1.K = 1536; d1.act = 1;
            gemm_mfma<<<dim3(32, 1, 1), blk, 0, stream>>>(d1);

            GemmArgs d2{};
            for (int s4 = 0; s4 < 4; ++s4) d2.seg[s4] = mkseg(a1_b + s4 * 512, 2048, 0);
            d2.nseg = 4; d2.segw_sh = 9;
            d2.Wt = decW2t + (size_t)j * 1536 * 2048;
            d2.bias = st_decb2 + j * 1536;
            d2.yf = a_f; d2.yb = nullptr; d2.y_rs = 1536; d2.y_zs = 0;
            d2.K = 2048; d2.act = 0;
            gemm_mfma<<<dim3(1536 / 64, 1, 1), blk, 0, stream>>>(d2);

            GateArgs gg{};
            gg.a = a_f; gg.W1 = 1024;
            gg.gw = st_decg + j * 1024; gg.gb = st_decbeta + j * 1024;
            gg.s0 = (j == 0) ? m_f : (chl_f + DD);
            gg.s0_rs = NS * DD;
            gg.s1 = nullptr; gg.s1_rs = 0;
            gg.out_f = chl_f + (j + 1) * DD; gg.out_b = chl_b + (j + 1) * DD; gg.out_rs = NS * DD;
            gate_k<<<dim3(BB), blk, 0, stream>>>(gg);
        }

        {
            FinArgs fa{};
            fa.chl = chl_f; fa.pp = pp; fa.task = task_f; fa.inp = inpf_t;
            fa.Wa = st_Wa; fa.ba = st_ba;
            fa.out = d_out; fa.o_base = (long)t * ACT;
            fa.flag = flag;
            final_k<<<dim3(BB), blk, 0, stream>>>(fa);
        }
    }
}